// Round 1
// baseline (416.948 us; speedup 1.0000x reference)
//
#include <hip/hip_runtime.h>
#include <hip/hip_bf16.h>

typedef unsigned short ushort_t;
typedef __attribute__((ext_vector_type(8))) short bf16x8;   // 8 bf16 = 4 VGPRs
typedef __attribute__((ext_vector_type(4))) float f32x4;    // 4 fp32 acc

#define MDIM 2048
#define NDIM 4096

// ---------------- prep: fp32 -> bf16 cast ----------------
__global__ void cast_bf16_kernel(const float* __restrict__ in, ushort_t* __restrict__ out, int n) {
    int i = blockIdx.x * blockDim.x + threadIdx.x;
    if (i < n) {
        __hip_bfloat16 h = __float2bfloat16(in[i]);
        out[i] = *reinterpret_cast<ushort_t*>(&h);
    }
}

// ---------------- prep: W[K][N] fp32 -> WT[N][K] bf16 ----------------
__global__ void transpose_cast_kernel(const float* __restrict__ W, ushort_t* __restrict__ WT,
                                      int K, int N) {
    __shared__ float tile[32][33];
    const int tx = threadIdx.x, ty = threadIdx.y;
    const int n0 = blockIdx.x * 32, k0 = blockIdx.y * 32;
#pragma unroll
    for (int r = 0; r < 4; ++r)
        tile[ty + r * 8][tx] = W[(size_t)(k0 + ty + r * 8) * N + n0 + tx];
    __syncthreads();
#pragma unroll
    for (int r = 0; r < 4; ++r) {
        __hip_bfloat16 h = __float2bfloat16(tile[tx][ty + r * 8]);
        WT[(size_t)(n0 + ty + r * 8) * K + k0 + tx] = *reinterpret_cast<ushort_t*>(&h);
    }
}

// ---------------- GEMM: C[M][N] = act(A[M][K] @ BT[N][K]^T + bias) ----------------
// 128x128 tile, BK=32, 4 waves (2x2), each wave 4x4 tiles of mfma_f32_16x16x32_bf16.
template <typename OutT, bool RELU>
__global__ __launch_bounds__(256, 2) void gemm_bt(const ushort_t* __restrict__ A,
                                                  const ushort_t* __restrict__ BT,
                                                  const float* __restrict__ bias,
                                                  OutT* __restrict__ C, int Kdim) {
    // LDA = 40 bf16 (80 B): 20-bank stride -> conflict-free b128 fragment reads
    __shared__ __align__(16) ushort_t As[128 * 40];
    __shared__ __align__(16) ushort_t Bs[128 * 40];

    const int t = threadIdx.x;
    const int m0 = blockIdx.y * 128;
    const int n0 = blockIdx.x * 128;
    const int lane = t & 63;
    const int wid = t >> 6;
    const int quad = lane >> 4;
    const int l16 = lane & 15;
    const int wm = (wid & 1) * 64;
    const int wn = (wid >> 1) * 64;

    f32x4 acc[4][4];
#pragma unroll
    for (int i = 0; i < 4; ++i)
#pragma unroll
        for (int j = 0; j < 4; ++j) acc[i][j] = (f32x4){0.f, 0.f, 0.f, 0.f};

    // staging: 128 rows x 32 cols bf16 = 512 chunks of 16B; 256 threads x 2 chunks
    const int row_a = t >> 2;  // 0..63 ; second chunk at +64
    const int cc = t & 3;      // 16B chunk within row

    for (int k0 = 0; k0 < Kdim; k0 += 32) {
        __syncthreads();
        uint4 av0 = *reinterpret_cast<const uint4*>(A + (size_t)(m0 + row_a) * Kdim + k0 + cc * 8);
        uint4 av1 = *reinterpret_cast<const uint4*>(A + (size_t)(m0 + row_a + 64) * Kdim + k0 + cc * 8);
        uint4 bv0 = *reinterpret_cast<const uint4*>(BT + (size_t)(n0 + row_a) * Kdim + k0 + cc * 8);
        uint4 bv1 = *reinterpret_cast<const uint4*>(BT + (size_t)(n0 + row_a + 64) * Kdim + k0 + cc * 8);
        *reinterpret_cast<uint4*>(&As[row_a * 40 + cc * 8]) = av0;
        *reinterpret_cast<uint4*>(&As[(row_a + 64) * 40 + cc * 8]) = av1;
        *reinterpret_cast<uint4*>(&Bs[row_a * 40 + cc * 8]) = bv0;
        *reinterpret_cast<uint4*>(&Bs[(row_a + 64) * 40 + cc * 8]) = bv1;
        __syncthreads();

        bf16x8 af[4], bfr[4];
#pragma unroll
        for (int i = 0; i < 4; ++i)
            af[i] = *reinterpret_cast<const bf16x8*>(&As[(wm + i * 16 + l16) * 40 + quad * 8]);
#pragma unroll
        for (int j = 0; j < 4; ++j)
            bfr[j] = *reinterpret_cast<const bf16x8*>(&Bs[(wn + j * 16 + l16) * 40 + quad * 8]);
#pragma unroll
        for (int i = 0; i < 4; ++i)
#pragma unroll
            for (int j = 0; j < 4; ++j)
                acc[i][j] = __builtin_amdgcn_mfma_f32_16x16x32_bf16(af[i], bfr[j], acc[i][j], 0, 0, 0);
    }

    // epilogue: C/D layout col=lane&15, row=quad*4+reg
#pragma unroll
    for (int i = 0; i < 4; ++i) {
#pragma unroll
        for (int r = 0; r < 4; ++r) {
            const int grow = m0 + wm + i * 16 + quad * 4 + r;
#pragma unroll
            for (int j = 0; j < 4; ++j) {
                const int gcol = n0 + wn + j * 16 + l16;
                float v = acc[i][j][r] + bias[gcol];
                if (RELU) v = fmaxf(v, 0.0f);
                if constexpr (sizeof(OutT) == 2) {
                    __hip_bfloat16 h = __float2bfloat16(v);
                    C[(size_t)grow * NDIM + gcol] = *reinterpret_cast<ushort_t*>(&h);
                } else {
                    C[(size_t)grow * NDIM + gcol] = v;
                }
            }
        }
    }
}

// ---------------- Sinkhorn: 1 wave = 1 matrix (64x64), 2 matrices/block ----------------
// LDS P padded to 65 floats/row: row pass stride 65 -> 2-way bank alias (free),
// col pass contiguous. Deferred col-factor: P in LDS always holds row-normalized
// state; pending col factor lives per-lane (cf) and is folded in next row pass.
__global__ __launch_bounds__(128) void sinkhorn_kernel(float* __restrict__ PM) {
    __shared__ __align__(16) float P[2][64 * 65];
    __shared__ float errbuf[2];
    const int t = threadIdx.x;
    const int w = t >> 6;
    const int l = t & 63;
    float* Pm = P[w];
    float* base = PM + (size_t)(blockIdx.x * 2 + w) * 4096;

    // load cost matrix, P0 = exp(-gamma*M); the reference's global /sum cancels
    // exactly in the first row-normalization, so it is skipped.
    for (int r = 0; r < 64; ++r)
        Pm[r * 65 + l] = expf(-base[r * 64 + l]);
    float cf = 1.0f;  // pending col factor for column l
    bool converged = false;
    __syncthreads();

    for (int it = 0; it < 1000; ++it) {
        // pass 1: lane l = row l. alpha = rowsum of (P * pending colfac)
        float alpha = 0.0f;
#pragma unroll
        for (int c = 0; c < 64; ++c)
            alpha = fmaf(Pm[l * 65 + c], __shfl(cf, c), alpha);
        const float rf = 0.015625f / alpha;  // r = 1/64

        // pass 2: lane l = col l. apply colfac+rowfac, write back, col sums
        float beta = 0.0f;
#pragma unroll
        for (int r = 0; r < 64; ++r) {
            float v = Pm[r * 65 + l] * cf * __shfl(rf, r);
            Pm[r * 65 + l] = v;
            beta += v;
        }
        float err = fabsf(beta - 0.015625f);  // c = 1/64
#pragma unroll
        for (int off = 32; off > 0; off >>= 1)
            err = fmaxf(err, __shfl_xor(err, off));
        if (l == 0) errbuf[w] = err;
        __syncthreads();
        const float gerr = fmaxf(errbuf[0], errbuf[1]);
        __syncthreads();
        if (gerr <= 1e-6f) {  // torch/jax loop: break BEFORE col-normalizing
            converged = true;
            break;
        }
        cf = 0.015625f / beta;  // deferred col-normalization
    }

    // writeback: if exited via maxiters with err>eps, the reference DID apply
    // the last col-normalization -> fold pending cf in.
    for (int r = 0; r < 64; ++r) {
        float v = Pm[r * 65 + l];
        if (!converged) v *= cf;
        base[r * 64 + l] = v;
    }
}

extern "C" void kernel_launch(void* const* d_in, const int* in_sizes, int n_in,
                              void* d_out, int out_size, void* d_ws, size_t ws_size,
                              hipStream_t stream) {
    const float* z  = (const float*)d_in[0];
    const float* W1 = (const float*)d_in[1];
    const float* b1 = (const float*)d_in[2];
    const float* W2 = (const float*)d_in[3];
    const float* b2 = (const float*)d_in[4];
    const float* W3 = (const float*)d_in[5];
    const float* b3 = (const float*)d_in[6];
    float* out = (float*)d_out;
    char* ws = (char*)d_ws;

    // workspace layout (bytes)
    ushort_t* W2T = (ushort_t*)(ws + 0);                       // 4096*4096*2 = 32 MB
    ushort_t* W3T = (ushort_t*)(ws + (size_t)33554432);        // 32 MB
    ushort_t* C1b = (ushort_t*)(ws + (size_t)67108864);        // 2048*4096*2 = 16 MB
    ushort_t* C2b = (ushort_t*)(ws + (size_t)83886080);        // 16 MB
    ushort_t* Zb  = (ushort_t*)(ws + (size_t)100663296);       // 2048*256*2 = 1 MB
    ushort_t* W1T = (ushort_t*)(ws + (size_t)101711872);       // 4096*256*2 = 2 MB

    // prep
    cast_bf16_kernel<<<2048, 256, 0, stream>>>(z, Zb, MDIM * 256);
    transpose_cast_kernel<<<dim3(128, 8), dim3(32, 8), 0, stream>>>(W1, W1T, 256, 4096);
    transpose_cast_kernel<<<dim3(128, 128), dim3(32, 8), 0, stream>>>(W2, W2T, 4096, 4096);
    transpose_cast_kernel<<<dim3(128, 128), dim3(32, 8), 0, stream>>>(W3, W3T, 4096, 4096);

    // 3-layer MLP (bf16 MFMA, fp32 accum); layer 3 writes fp32 cost matrix into d_out
    gemm_bt<ushort_t, true><<<dim3(NDIM / 128, MDIM / 128), 256, 0, stream>>>(Zb, W1T, b1, C1b, 256);
    gemm_bt<ushort_t, true><<<dim3(NDIM / 128, MDIM / 128), 256, 0, stream>>>(C1b, W2T, b2, C2b, 4096);
    gemm_bt<float, false><<<dim3(NDIM / 128, MDIM / 128), 256, 0, stream>>>(C2b, W3T, b3, out, 4096);

    // Sinkhorn in-place on d_out
    sinkhorn_kernel<<<1024, 128, 0, stream>>>(out);
}

// Round 3
// 408.596 us; speedup vs baseline: 1.0204x; 1.0204x over previous
//
#include <hip/hip_runtime.h>
#include <hip/hip_bf16.h>

typedef unsigned short ushort_t;
typedef __attribute__((ext_vector_type(8))) short bf16x8;   // 8 bf16 = 4 VGPRs
typedef __attribute__((ext_vector_type(4))) float f32x4;    // 4 fp32 acc

#define MDIM 2048
#define NDIM 4096

// ---------------- prep: fp32 -> bf16 cast ----------------
__global__ void cast_bf16_kernel(const float* __restrict__ in, ushort_t* __restrict__ out, int n) {
    int i = blockIdx.x * blockDim.x + threadIdx.x;
    if (i < n) {
        __hip_bfloat16 h = __float2bfloat16(in[i]);
        out[i] = *reinterpret_cast<ushort_t*>(&h);
    }
}

// ---------------- prep: W[K][N] fp32 -> WT[N][K] bf16 ----------------
__global__ void transpose_cast_kernel(const float* __restrict__ W, ushort_t* __restrict__ WT,
                                      int K, int N) {
    __shared__ float tile[32][33];
    const int tx = threadIdx.x, ty = threadIdx.y;
    const int n0 = blockIdx.x * 32, k0 = blockIdx.y * 32;
#pragma unroll
    for (int r = 0; r < 4; ++r)
        tile[ty + r * 8][tx] = W[(size_t)(k0 + ty + r * 8) * N + n0 + tx];
    __syncthreads();
#pragma unroll
    for (int r = 0; r < 4; ++r) {
        __hip_bfloat16 h = __float2bfloat16(tile[tx][ty + r * 8]);
        WT[(size_t)(n0 + ty + r * 8) * K + k0 + tx] = *reinterpret_cast<ushort_t*>(&h);
    }
}

// ---------------- GEMM: C[M][N] = act(A[M][K] @ BT[N][K]^T + bias) ----------------
// 128x128 tile, BK=32, 4 waves (2x2), each wave 4x4 tiles of mfma_f32_16x16x32_bf16.
// R1-proven version (vector-load staging into padded LDS). The global_load_lds
// DMA variant (R2) raced under graph replay — do not reintroduce without a
// verified fix.
template <typename OutT, bool RELU>
__global__ __launch_bounds__(256, 2) void gemm_bt(const ushort_t* __restrict__ A,
                                                  const ushort_t* __restrict__ BT,
                                                  const float* __restrict__ bias,
                                                  OutT* __restrict__ C, int Kdim) {
    // LDA = 40 bf16 (80 B): 20-bank stride -> conflict-free b128 fragment reads
    __shared__ __align__(16) ushort_t As[128 * 40];
    __shared__ __align__(16) ushort_t Bs[128 * 40];

    const int t = threadIdx.x;
    const int m0 = blockIdx.y * 128;
    const int n0 = blockIdx.x * 128;
    const int lane = t & 63;
    const int wid = t >> 6;
    const int quad = lane >> 4;
    const int l16 = lane & 15;
    const int wm = (wid & 1) * 64;
    const int wn = (wid >> 1) * 64;

    f32x4 acc[4][4];
#pragma unroll
    for (int i = 0; i < 4; ++i)
#pragma unroll
        for (int j = 0; j < 4; ++j) acc[i][j] = (f32x4){0.f, 0.f, 0.f, 0.f};

    // staging: 128 rows x 32 cols bf16 = 512 chunks of 16B; 256 threads x 2 chunks
    const int row_a = t >> 2;  // 0..63 ; second chunk at +64
    const int cc = t & 3;      // 16B chunk within row

    for (int k0 = 0; k0 < Kdim; k0 += 32) {
        __syncthreads();
        uint4 av0 = *reinterpret_cast<const uint4*>(A + (size_t)(m0 + row_a) * Kdim + k0 + cc * 8);
        uint4 av1 = *reinterpret_cast<const uint4*>(A + (size_t)(m0 + row_a + 64) * Kdim + k0 + cc * 8);
        uint4 bv0 = *reinterpret_cast<const uint4*>(BT + (size_t)(n0 + row_a) * Kdim + k0 + cc * 8);
        uint4 bv1 = *reinterpret_cast<const uint4*>(BT + (size_t)(n0 + row_a + 64) * Kdim + k0 + cc * 8);
        *reinterpret_cast<uint4*>(&As[row_a * 40 + cc * 8]) = av0;
        *reinterpret_cast<uint4*>(&As[(row_a + 64) * 40 + cc * 8]) = av1;
        *reinterpret_cast<uint4*>(&Bs[row_a * 40 + cc * 8]) = bv0;
        *reinterpret_cast<uint4*>(&Bs[(row_a + 64) * 40 + cc * 8]) = bv1;
        __syncthreads();

        bf16x8 af[4], bfr[4];
#pragma unroll
        for (int i = 0; i < 4; ++i)
            af[i] = *reinterpret_cast<const bf16x8*>(&As[(wm + i * 16 + l16) * 40 + quad * 8]);
#pragma unroll
        for (int j = 0; j < 4; ++j)
            bfr[j] = *reinterpret_cast<const bf16x8*>(&Bs[(wn + j * 16 + l16) * 40 + quad * 8]);
#pragma unroll
        for (int i = 0; i < 4; ++i)
#pragma unroll
            for (int j = 0; j < 4; ++j)
                acc[i][j] = __builtin_amdgcn_mfma_f32_16x16x32_bf16(af[i], bfr[j], acc[i][j], 0, 0, 0);
    }

    // epilogue: C/D layout col=lane&15, row=quad*4+reg
#pragma unroll
    for (int i = 0; i < 4; ++i) {
#pragma unroll
        for (int r = 0; r < 4; ++r) {
            const int grow = m0 + wm + i * 16 + quad * 4 + r;
#pragma unroll
            for (int j = 0; j < 4; ++j) {
                const int gcol = n0 + wn + j * 16 + l16;
                float v = acc[i][j][r] + bias[gcol];
                if (RELU) v = fmaxf(v, 0.0f);
                if constexpr (sizeof(OutT) == 2) {
                    __hip_bfloat16 h = __float2bfloat16(v);
                    C[(size_t)grow * NDIM + gcol] = *reinterpret_cast<ushort_t*>(&h);
                } else {
                    C[(size_t)grow * NDIM + gcol] = v;
                }
            }
        }
    }
}

// ---------------- Sinkhorn, factored: P = diag(a) K diag(b) ----------------
// One wave per matrix. K held in REGISTERS both ways: lane l keeps row l
// (Krow, for K*b) and column l (Kcol, for K^T*a). Iteration loop is pure
// VALU + readlane: no LDS, no barriers. Identity with the reference:
//   a <- (1/64)/(K b)    (row normalize)
//   beta = b * (K^T a);  err = max|beta - 1/64|; break BEFORE b update
//   b <- (1/64)/(K^T a)  (col normalize)
// Final P[r][c] = a_r K[r][c] b_c; maxiters path uses the updated b, matching
// the reference's "where(err<=eps, P, P*(c/beta))" semantics.
__device__ __forceinline__ float rdl(float v, int l) {
    return __uint_as_float(__builtin_amdgcn_readlane(__float_as_uint(v), l));
}

__global__ __launch_bounds__(64) void sinkhorn_kernel(float* __restrict__ PM) {
    __shared__ __align__(16) float T[64 * 65];  // one-time transpose staging
    const int l = threadIdx.x;
    float* base = PM + (size_t)blockIdx.x * 4096;

    float Kcol[64];  // Kcol[r] = K[r][l]  (column l)
    float Krow[64];  // Krow[c] = K[l][c]  (row l)
#pragma unroll
    for (int r = 0; r < 64; ++r)
        Kcol[r] = __expf(-base[r * 64 + l]);  // coalesced; global /sum cancels in 1st row-norm
#pragma unroll
    for (int r = 0; r < 64; ++r)
        T[r * 65 + l] = Kcol[r];
    __syncthreads();
#pragma unroll
    for (int c = 0; c < 64; ++c)
        Krow[c] = T[l * 65 + c];  // stride-65: 2-way bank alias (free)

    float a = 0.0f, b = 1.0f;
    for (int it = 0; it < 1000; ++it) {
        float t1 = 0.0f;  // (K b)_row=l
#pragma unroll
        for (int c = 0; c < 64; ++c)
            t1 = fmaf(Krow[c], rdl(b, c), t1);
        a = 0.015625f / t1;  // r = 1/64

        float t2 = 0.0f;  // (K^T a)_col=l
#pragma unroll
        for (int r = 0; r < 64; ++r)
            t2 = fmaf(Kcol[r], rdl(a, r), t2);
        const float err = fabsf(b * t2 - 0.015625f);  // beta_c - c
        if (__ballot(err > 1e-6f) == 0ull) break;     // max over lanes <= eps
        b = 0.015625f / t2;
    }

    // writeback: P[r][l] = a_r * K[r][l] * b_l, coalesced per row
#pragma unroll
    for (int r = 0; r < 64; ++r)
        base[r * 64 + l] = rdl(a, r) * Kcol[r] * b;
}

extern "C" void kernel_launch(void* const* d_in, const int* in_sizes, int n_in,
                              void* d_out, int out_size, void* d_ws, size_t ws_size,
                              hipStream_t stream) {
    const float* z  = (const float*)d_in[0];
    const float* W1 = (const float*)d_in[1];
    const float* b1 = (const float*)d_in[2];
    const float* W2 = (const float*)d_in[3];
    const float* b2 = (const float*)d_in[4];
    const float* W3 = (const float*)d_in[5];
    const float* b3 = (const float*)d_in[6];
    float* out = (float*)d_out;
    char* ws = (char*)d_ws;

    // workspace layout (bytes)
    ushort_t* W2T = (ushort_t*)(ws + 0);                       // 4096*4096*2 = 32 MB
    ushort_t* W3T = (ushort_t*)(ws + (size_t)33554432);        // 32 MB
    ushort_t* C1b = (ushort_t*)(ws + (size_t)67108864);        // 2048*4096*2 = 16 MB
    ushort_t* C2b = (ushort_t*)(ws + (size_t)83886080);        // 16 MB
    ushort_t* Zb  = (ushort_t*)(ws + (size_t)100663296);       // 2048*256*2 = 1 MB
    ushort_t* W1T = (ushort_t*)(ws + (size_t)101711872);       // 4096*256*2 = 2 MB

    // prep
    cast_bf16_kernel<<<2048, 256, 0, stream>>>(z, Zb, MDIM * 256);
    transpose_cast_kernel<<<dim3(128, 8), dim3(32, 8), 0, stream>>>(W1, W1T, 256, 4096);
    transpose_cast_kernel<<<dim3(128, 128), dim3(32, 8), 0, stream>>>(W2, W2T, 4096, 4096);
    transpose_cast_kernel<<<dim3(128, 128), dim3(32, 8), 0, stream>>>(W3, W3T, 4096, 4096);

    // 3-layer MLP (bf16 MFMA, fp32 accum); layer 3 writes fp32 cost matrix into d_out
    gemm_bt<ushort_t, true><<<dim3(NDIM / 128, MDIM / 128), 256, 0, stream>>>(Zb, W1T, b1, C1b, 256);
    gemm_bt<ushort_t, true><<<dim3(NDIM / 128, MDIM / 128), 256, 0, stream>>>(C1b, W2T, b2, C2b, 4096);
    gemm_bt<float, false><<<dim3(NDIM / 128, MDIM / 128), 256, 0, stream>>>(C2b, W3T, b3, out, 4096);

    // Sinkhorn in-place on d_out (one wave per matrix, register-resident K)
    sinkhorn_kernel<<<2048, 64, 0, stream>>>(out);
}

// Round 4
// 385.327 us; speedup vs baseline: 1.0821x; 1.0604x over previous
//
#include <hip/hip_runtime.h>
#include <hip/hip_bf16.h>

typedef unsigned short ushort_t;
typedef __attribute__((ext_vector_type(8))) short bf16x8;   // 8 bf16 = 4 VGPRs
typedef __attribute__((ext_vector_type(4))) float f32x4;    // 4 fp32 acc

#define MDIM 2048
#define NDIM 4096

__device__ __forceinline__ ushort_t to_bf16(float f) {
    __hip_bfloat16 h = __float2bfloat16(f);
    return *reinterpret_cast<ushort_t*>(&h);
}

// ---------------- prep: fp32 -> bf16 cast ----------------
__global__ void cast_bf16_kernel(const float* __restrict__ in, ushort_t* __restrict__ out, int n) {
    int i = blockIdx.x * blockDim.x + threadIdx.x;
    if (i < n) out[i] = to_bf16(in[i]);
}

// ---------------- prep: W[K][N] fp32 -> WT[N][K] bf16 ----------------
// 32x32 tile; coalesced fp32 loads, ushort4 (4-k) stores: 8 consecutive threads
// cover one n-row's 32 k's contiguously (64B). LDS reads are 2-way aliased (free).
__global__ void transpose_cast_kernel(const float* __restrict__ W, ushort_t* __restrict__ WT,
                                      int K, int N) {
    __shared__ float tile[32][33];
    const int tx = threadIdx.x, ty = threadIdx.y;  // (32, 8)
    const int n0 = blockIdx.x * 32, k0 = blockIdx.y * 32;
#pragma unroll
    for (int r = 0; r < 4; ++r)
        tile[ty + r * 8][tx] = W[(size_t)(k0 + ty + r * 8) * N + n0 + tx];
    __syncthreads();
    const int t = ty * 32 + tx;
    const int nl = t >> 3;          // 0..31 : local n
    const int kc = (t & 7) * 4;     // 0..28 : k chunk of 4
    ushort4 o;
    o.x = to_bf16(tile[kc + 0][nl]);
    o.y = to_bf16(tile[kc + 1][nl]);
    o.z = to_bf16(tile[kc + 2][nl]);
    o.w = to_bf16(tile[kc + 3][nl]);
    *reinterpret_cast<ushort4*>(&WT[(size_t)(n0 + nl) * K + k0 + kc]) = o;
}

// ---------------- GEMM: C[M][N] = act(A[M][K] @ BT[N][K]^T + bias) ----------------
// 128x128 tile, BK=32, 4 waves (2x2), each wave 4x4 tiles of mfma_f32_16x16x32_bf16.
// Register double-buffer: tile k+1 is loaded into VGPRs while tile k computes,
// so global-load latency overlaps the MFMA phase instead of sitting on the
// critical path (we are grid-limited to 2 blocks/CU at M=2048, so implicit
// wave-overlap alone cannot hide it). LDS stays single-buffered (LDA=40 pad,
// conflict-free b128 fragment reads).
template <typename OutT, bool RELU>
__global__ __launch_bounds__(256, 2) void gemm_bt(const ushort_t* __restrict__ A,
                                                  const ushort_t* __restrict__ BT,
                                                  const float* __restrict__ bias,
                                                  OutT* __restrict__ C, int Kdim) {
    __shared__ __align__(16) ushort_t As[128 * 40];
    __shared__ __align__(16) ushort_t Bs[128 * 40];

    const int t = threadIdx.x;
    const int m0 = blockIdx.y * 128;
    const int n0 = blockIdx.x * 128;
    const int lane = t & 63;
    const int wid = t >> 6;
    const int quad = lane >> 4;
    const int l16 = lane & 15;
    const int wm = (wid & 1) * 64;
    const int wn = (wid >> 1) * 64;

    f32x4 acc[4][4];
#pragma unroll
    for (int i = 0; i < 4; ++i)
#pragma unroll
        for (int j = 0; j < 4; ++j) acc[i][j] = (f32x4){0.f, 0.f, 0.f, 0.f};

    // staging: 128 rows x 32 cols bf16 = 512 chunks of 16B; 256 threads x 2 chunks
    const int row_a = t >> 2;  // 0..63 ; second chunk at +64
    const int cc = t & 3;      // 16B chunk within row

    const ushort_t* pA0 = A + (size_t)(m0 + row_a) * Kdim + cc * 8;
    const ushort_t* pA1 = A + (size_t)(m0 + row_a + 64) * Kdim + cc * 8;
    const ushort_t* pB0 = BT + (size_t)(n0 + row_a) * Kdim + cc * 8;
    const ushort_t* pB1 = BT + (size_t)(n0 + row_a + 64) * Kdim + cc * 8;

    // prefetch tile 0 into registers
    uint4 av0 = *reinterpret_cast<const uint4*>(pA0);
    uint4 av1 = *reinterpret_cast<const uint4*>(pA1);
    uint4 bv0 = *reinterpret_cast<const uint4*>(pB0);
    uint4 bv1 = *reinterpret_cast<const uint4*>(pB1);

    for (int k0 = 0; k0 < Kdim; k0 += 32) {
        __syncthreads();  // all waves done reading previous LDS tile
        *reinterpret_cast<uint4*>(&As[row_a * 40 + cc * 8]) = av0;
        *reinterpret_cast<uint4*>(&As[(row_a + 64) * 40 + cc * 8]) = av1;
        *reinterpret_cast<uint4*>(&Bs[row_a * 40 + cc * 8]) = bv0;
        *reinterpret_cast<uint4*>(&Bs[(row_a + 64) * 40 + cc * 8]) = bv1;
        __syncthreads();  // tile k visible

        // prefetch tile k+1 (no dependence on the MFMAs below -> overlaps them)
        if (k0 + 32 < Kdim) {
            av0 = *reinterpret_cast<const uint4*>(pA0 + k0 + 32);
            av1 = *reinterpret_cast<const uint4*>(pA1 + k0 + 32);
            bv0 = *reinterpret_cast<const uint4*>(pB0 + k0 + 32);
            bv1 = *reinterpret_cast<const uint4*>(pB1 + k0 + 32);
        }

        bf16x8 af[4], bfr[4];
#pragma unroll
        for (int i = 0; i < 4; ++i)
            af[i] = *reinterpret_cast<const bf16x8*>(&As[(wm + i * 16 + l16) * 40 + quad * 8]);
#pragma unroll
        for (int j = 0; j < 4; ++j)
            bfr[j] = *reinterpret_cast<const bf16x8*>(&Bs[(wn + j * 16 + l16) * 40 + quad * 8]);
#pragma unroll
        for (int i = 0; i < 4; ++i)
#pragma unroll
            for (int j = 0; j < 4; ++j)
                acc[i][j] = __builtin_amdgcn_mfma_f32_16x16x32_bf16(af[i], bfr[j], acc[i][j], 0, 0, 0);
    }

    // epilogue: C/D layout col=lane&15, row=quad*4+reg
#pragma unroll
    for (int i = 0; i < 4; ++i) {
#pragma unroll
        for (int r = 0; r < 4; ++r) {
            const int grow = m0 + wm + i * 16 + quad * 4 + r;
#pragma unroll
            for (int j = 0; j < 4; ++j) {
                const int gcol = n0 + wn + j * 16 + l16;
                float v = acc[i][j][r] + bias[gcol];
                if (RELU) v = fmaxf(v, 0.0f);
                if constexpr (sizeof(OutT) == 2) {
                    C[(size_t)grow * NDIM + gcol] = to_bf16(v);
                } else {
                    C[(size_t)grow * NDIM + gcol] = v;
                }
            }
        }
    }
}

// ---------------- Sinkhorn, factored: P = diag(a) K diag(b) ----------------
// One wave per matrix. K held in REGISTERS both ways: lane l keeps row l
// (Krow, for K*b) and column l (Kcol, for K^T*a). Iteration loop is pure
// VALU + readlane: no LDS, no barriers. Identity with the reference:
//   a <- (1/64)/(K b)    (row normalize)
//   beta = b * (K^T a);  err = max|beta - 1/64|; break BEFORE b update
//   b <- (1/64)/(K^T a)  (col normalize)
// Final P[r][c] = a_r K[r][c] b_c; maxiters path uses the updated b, matching
// the reference's "where(err<=eps, P, P*(c/beta))" semantics.
__device__ __forceinline__ float rdl(float v, int l) {
    return __uint_as_float(__builtin_amdgcn_readlane(__float_as_uint(v), l));
}

__global__ __launch_bounds__(64) void sinkhorn_kernel(float* __restrict__ PM) {
    __shared__ __align__(16) float T[64 * 65];  // one-time transpose staging
    const int l = threadIdx.x;
    float* base = PM + (size_t)blockIdx.x * 4096;

    float Kcol[64];  // Kcol[r] = K[r][l]  (column l)
    float Krow[64];  // Krow[c] = K[l][c]  (row l)
#pragma unroll
    for (int r = 0; r < 64; ++r)
        Kcol[r] = __expf(-base[r * 64 + l]);  // coalesced; global /sum cancels in 1st row-norm
#pragma unroll
    for (int r = 0; r < 64; ++r)
        T[r * 65 + l] = Kcol[r];
    __syncthreads();
#pragma unroll
    for (int c = 0; c < 64; ++c)
        Krow[c] = T[l * 65 + c];  // stride-65: 2-way bank alias (free)

    float a = 0.0f, b = 1.0f;
    for (int it = 0; it < 1000; ++it) {
        float t1 = 0.0f;  // (K b)_row=l
#pragma unroll
        for (int c = 0; c < 64; ++c)
            t1 = fmaf(Krow[c], rdl(b, c), t1);
        a = 0.015625f / t1;  // r = 1/64

        float t2 = 0.0f;  // (K^T a)_col=l
#pragma unroll
        for (int r = 0; r < 64; ++r)
            t2 = fmaf(Kcol[r], rdl(a, r), t2);
        const float err = fabsf(b * t2 - 0.015625f);  // beta_c - c
        if (__ballot(err > 1e-6f) == 0ull) break;     // max over lanes <= eps
        b = 0.015625f / t2;
    }

    // writeback: P[r][l] = a_r * K[r][l] * b_l, coalesced per row
#pragma unroll
    for (int r = 0; r < 64; ++r)
        base[r * 64 + l] = rdl(a, r) * Kcol[r] * b;
}

extern "C" void kernel_launch(void* const* d_in, const int* in_sizes, int n_in,
                              void* d_out, int out_size, void* d_ws, size_t ws_size,
                              hipStream_t stream) {
    const float* z  = (const float*)d_in[0];
    const float* W1 = (const float*)d_in[1];
    const float* b1 = (const float*)d_in[2];
    const float* W2 = (const float*)d_in[3];
    const float* b2 = (const float*)d_in[4];
    const float* W3 = (const float*)d_in[5];
    const float* b3 = (const float*)d_in[6];
    float* out = (float*)d_out;
    char* ws = (char*)d_ws;

    // workspace layout (bytes)
    ushort_t* W2T = (ushort_t*)(ws + 0);                       // 4096*4096*2 = 32 MB
    ushort_t* W3T = (ushort_t*)(ws + (size_t)33554432);        // 32 MB
    ushort_t* C1b = (ushort_t*)(ws + (size_t)67108864);        // 2048*4096*2 = 16 MB
    ushort_t* C2b = (ushort_t*)(ws + (size_t)83886080);        // 16 MB
    ushort_t* Zb  = (ushort_t*)(ws + (size_t)100663296);       // 2048*256*2 = 1 MB
    ushort_t* W1T = (ushort_t*)(ws + (size_t)101711872);       // 4096*256*2 = 2 MB

    // prep
    cast_bf16_kernel<<<2048, 256, 0, stream>>>(z, Zb, MDIM * 256);
    transpose_cast_kernel<<<dim3(128, 8), dim3(32, 8), 0, stream>>>(W1, W1T, 256, 4096);
    transpose_cast_kernel<<<dim3(128, 128), dim3(32, 8), 0, stream>>>(W2, W2T, 4096, 4096);
    transpose_cast_kernel<<<dim3(128, 128), dim3(32, 8), 0, stream>>>(W3, W3T, 4096, 4096);

    // 3-layer MLP (bf16 MFMA, fp32 accum); layer 3 writes fp32 cost matrix into d_out
    gemm_bt<ushort_t, true><<<dim3(NDIM / 128, MDIM / 128), 256, 0, stream>>>(Zb, W1T, b1, C1b, 256);
    gemm_bt<ushort_t, true><<<dim3(NDIM / 128, MDIM / 128), 256, 0, stream>>>(C1b, W2T, b2, C2b, 4096);
    gemm_bt<float, false><<<dim3(NDIM / 128, MDIM / 128), 256, 0, stream>>>(C2b, W3T, b3, out, 4096);

    // Sinkhorn in-place on d_out (one wave per matrix, register-resident K)
    sinkhorn_kernel<<<2048, 64, 0, stream>>>(out);
}